// Round 8
// baseline (124.333 us; speedup 1.0000x reference)
//
#include <hip/hip_runtime.h>
#include <hip/hip_bf16.h>
#include <stdint.h>

#define N_PTS 4096
#define DIM 512
#define MARGIN_F 0.3f
#define POS_INF_BITS 0x7f800000

#define BM 128
#define BN 128
#define BK 32
#define STRIPS 8                 // gridDim.x
#define JTILES 4                 // j-tiles per block (strip width 512)
#define NPART (STRIPS * JTILES * 2)   // 64 partials per row
#define NSTEP (JTILES * (DIM / BK))   // 64 pipeline steps

typedef short bf16x8 __attribute__((ext_vector_type(8)));
typedef float f32x4 __attribute__((ext_vector_type(4)));

__device__ __forceinline__ unsigned short f2bf(float f) {
    unsigned int b = __float_as_uint(f);
    b += 0x7FFF + ((b >> 16) & 1);   // round-to-nearest-even
    return (unsigned short)(b >> 16);
}

// async global->LDS, 16B per lane; LDS dest must be wave-uniform base (+lane*16)
__device__ __forceinline__ void async16(const unsigned short* g, unsigned short* l) {
    __builtin_amdgcn_global_load_lds(
        (const __attribute__((address_space(1))) unsigned int*)g,
        (__attribute__((address_space(3))) unsigned int*)l,
        16, 0, 0);
}

// One wave per row: bf16 copy + exact fp32 norms; zero the output accumulator.
__global__ __launch_bounds__(256) void prep_kernel(
    const float* __restrict__ src, const float* __restrict__ tgt,
    unsigned short* __restrict__ src_bf, unsigned short* __restrict__ tgt_bf,
    float* __restrict__ e1, float* __restrict__ e2,
    float* __restrict__ out)
{
    const int row  = blockIdx.x * 4 + (threadIdx.x >> 6);
    const int lane = threadIdx.x & 63;

    if (blockIdx.x == 0 && threadIdx.x == 0) out[0] = 0.0f;

    const float4* s4 = (const float4*)(src + (size_t)row * DIM);
    const float4* t4 = (const float4*)(tgt + (size_t)row * DIM);
    float4 a0 = s4[lane], a1 = s4[lane + 64];
    float4 b0 = t4[lane], b1 = t4[lane + 64];

    ushort4 u;
    ushort4* so = (ushort4*)(src_bf + (size_t)row * DIM);
    ushort4* to = (ushort4*)(tgt_bf + (size_t)row * DIM);
    u.x = f2bf(a0.x); u.y = f2bf(a0.y); u.z = f2bf(a0.z); u.w = f2bf(a0.w); so[lane] = u;
    u.x = f2bf(a1.x); u.y = f2bf(a1.y); u.z = f2bf(a1.z); u.w = f2bf(a1.w); so[lane + 64] = u;
    u.x = f2bf(b0.x); u.y = f2bf(b0.y); u.z = f2bf(b0.z); u.w = f2bf(b0.w); to[lane] = u;
    u.x = f2bf(b1.x); u.y = f2bf(b1.y); u.z = f2bf(b1.z); u.w = f2bf(b1.w); to[lane + 64] = u;

    float s1 = a0.x*a0.x + a0.y*a0.y + a0.z*a0.z + a0.w*a0.w
             + a1.x*a1.x + a1.y*a1.y + a1.z*a1.z + a1.w*a1.w;
    float s2 = b0.x*b0.x + b0.y*b0.y + b0.z*b0.z + b0.w*b0.w
             + b1.x*b1.x + b1.y*b1.y + b1.z*b1.z + b1.w*b1.w;
    for (int off = 32; off; off >>= 1) {
        s1 += __shfl_down(s1, off);
        s2 += __shfl_down(s2, off);
    }
    if (lane == 0) {
        e1[row] = s1;
        e2[row] = s2;
    }
}

// Persistent-A-panel GEMM: 256 blocks (1/CU), each owns a 128-row A panel
// staged ONCE into LDS (128 KiB, full K — barrier-free reads thereafter) and
// streams B through a double-buffered 8 KiB K-slice. One barrier per step;
// its vmcnt(0) drains a prefetch issued a full compute-phase earlier, so L2
// latency is hidden (the structure m97's 2-barrier loop cannot express).
// Lessons kept: no device-scope fences (r4), no shared-line atomics (r6),
// XOR-swizzled chunk layout applied on the GLOBAL gather (r3: 0 conflicts).
__global__ __launch_bounds__(256) void dist_kernel(
    const unsigned short* __restrict__ src_bf,
    const unsigned short* __restrict__ tgt_bf,
    const float* __restrict__ e1, const float* __restrict__ e2,
    const int* __restrict__ labels,
    float* __restrict__ ap_part, float* __restrict__ an_part)
{
    __shared__ unsigned short As[BM * DIM];      // 128 KiB full-K A panel
    __shared__ unsigned short Bs[2][BN * BK];    // 2 x 8 KiB B K-slices
    __shared__ int   li[BM];
    __shared__ float e1s[BM];
    __shared__ int   lj_all[JTILES * BN];        // strip's 512 labels
    __shared__ float e2s_all[JTILES * BN];

    const int i0    = blockIdx.y * BM;
    const int jbase = blockIdx.x * (JTILES * BN);
    const int t     = threadIdx.x;
    const int lane  = t & 63;
    const int wave  = t >> 6;

    if (t < BM) { li[t] = labels[i0 + t]; e1s[t] = e1[i0 + t]; }
    lj_all[t]        = labels[jbase + t];
    lj_all[t + 256]  = labels[jbase + t + 256];
    e2s_all[t]       = e2[jbase + t];
    e2s_all[t + 256] = e2[jbase + t + 256];

    // ---- A panel staging (once): wave w stages rows [w*32, w*32+32), one row
    // (64 x 16B chunks) per async16; lane = physical chunk. Physical chunk p
    // holds logical chunk p ^ (row&7): ds_read_b128 start banks then cover all
    // 8 x4-bank groups (2 lanes each) -> 2-way aliasing only = free (m136).
    #pragma unroll
    for (int it = 0; it < 32; it++) {
        const int row = wave * 32 + it;                    // wave-uniform
        const unsigned short* g = src_bf + (size_t)(i0 + row) * DIM
                                + ((lane ^ (row & 7)) * 8);
        async16(g, &As[row * DIM]);
    }

    // ---- B staging map (per step): thread t covers chunk t (rows 0..63) and
    // t+256 (rows 64..127); phys col chunk t&3 holds logical (t&3)^((srow>>1)&3).
    const int srow  = t >> 2;
    const int scoff = ((t & 3) ^ ((srow >> 1) & 3)) * 8;
    const unsigned short* gB0 = tgt_bf + (size_t)srow * DIM + scoff;
    const unsigned short* gB1 = tgt_bf + (size_t)(64 + srow) * DIM + scoff;

    // wave -> 64x64 subtile: 4x4 of 16x16x32 MFMA
    const int wm = (wave >> 1) * 64;
    const int wn = (wave & 1) * 64;
    const int fr = lane & 15;
    const int quad = lane >> 4;
    const int fkeyA = fr & 7;
    const int cpB = ((quad ^ ((fr >> 1) & 3))) * 8;        // B phys chunk off

    f32x4 acc[4][4];
    #pragma unroll
    for (int a = 0; a < 4; a++)
        #pragma unroll
        for (int b = 0; b < 4; b++)
            acc[a][b] = (f32x4){0.f, 0.f, 0.f, 0.f};

    // prologue: B step 0 into buf 0, then one drain for A + B0 + LDS scalars
    {
        const size_t off0 = (size_t)jbase * DIM;           // jt=0, k=0
        async16(gB0 + off0, &Bs[0][0] + wave * 512);
        async16(gB1 + off0, &Bs[0][0] + 2048 + wave * 512);
    }
    __syncthreads();

    const float INF = __int_as_float(POS_INF_BITS);

    #pragma unroll 4
    for (int s = 0; s < NSTEP; s++) {
        // prefetch step s+1 into the other buffer (readers finished last iter)
        if (s + 1 < NSTEP) {
            const int s1 = s + 1;
            const size_t off = (size_t)(jbase + (s1 >> 4) * BN) * DIM
                             + (size_t)(s1 & 15) * BK;
            unsigned short* dst = &Bs[s1 & 1][0];
            async16(gB0 + off, dst + wave * 512);
            async16(gB1 + off, dst + 2048 + wave * 512);
        }

        const int k0 = s & 15;
        const unsigned short* bb = &Bs[s & 1][0];
        const int cpA = (((k0 << 2) | quad) ^ fkeyA) * 8;  // A phys chunk off

        bf16x8 af[4], bf[4];
        #pragma unroll
        for (int x = 0; x < 4; x++) {
            af[x] = *(const bf16x8*)&As[(wm + x * 16 + fr) * DIM + cpA];
            bf[x] = *(const bf16x8*)&bb[(wn + x * 16 + fr) * BK + cpB];
        }
        #pragma unroll
        for (int tm = 0; tm < 4; tm++)
            #pragma unroll
            for (int tn = 0; tn < 4; tn++)
                acc[tm][tn] = __builtin_amdgcn_mfma_f32_16x16x32_bf16(
                    af[tm], bf[tn], acc[tm][tn], 0, 0, 0);

        if (k0 == 15) {   // j-tile finished: epilogue + acc reset
            const int jt = s >> 4;
            const int pcol = (blockIdx.x * JTILES + jt) * 2 + (wave & 1);
            #pragma unroll
            for (int tm = 0; tm < 4; tm++) {
                #pragma unroll
                for (int r = 0; r < 4; r++) {
                    const int rl = wm + tm * 16 + quad * 4 + r;
                    const float e1v = e1s[rl];
                    const int   liv = li[rl];
                    float apv = 0.0f, anv = INF;
                    #pragma unroll
                    for (int tn = 0; tn < 4; tn++) {
                        const int cl = jt * BN + wn + tn * 16 + fr;
                        float d = e1v + e2s_all[cl] - 2.0f * acc[tm][tn][r];
                        d = fmaxf(d, 0.0f);
                        if (liv == lj_all[cl]) apv = fmaxf(apv, d);
                        else                   anv = fminf(anv, d);
                    }
                    #pragma unroll
                    for (int off = 1; off < 16; off <<= 1) {
                        apv = fmaxf(apv, __shfl_xor(apv, off));
                        anv = fminf(anv, __shfl_xor(anv, off));
                    }
                    if (fr == 0) {
                        ap_part[(size_t)(i0 + rl) * NPART + pcol] = apv;
                        an_part[(size_t)(i0 + rl) * NPART + pcol] = anv;
                    }
                }
            }
            #pragma unroll
            for (int a = 0; a < 4; a++)
                #pragma unroll
                for (int b = 0; b < 4; b++)
                    acc[a][b] = (f32x4){0.f, 0.f, 0.f, 0.f};
        }

        __syncthreads();   // swap point; drains the long-since-landed prefetch
    }
}

// 32 blocks x 128 threads; thread = one row: reduce 64 partials, relu, sum.
__global__ __launch_bounds__(128) void loss_kernel(
    const float* __restrict__ ap_part, const float* __restrict__ an_part,
    float* __restrict__ out)
{
    const int row = blockIdx.x * 128 + threadIdx.x;
    const float4* a4 = (const float4*)(ap_part + (size_t)row * NPART);
    const float4* n4 = (const float4*)(an_part + (size_t)row * NPART);
    float apv = 0.0f;
    float anv = __int_as_float(POS_INF_BITS);
    #pragma unroll
    for (int i = 0; i < NPART / 4; i++) {
        float4 a = a4[i], n = n4[i];
        apv = fmaxf(apv, fmaxf(fmaxf(a.x, a.y), fmaxf(a.z, a.w)));
        anv = fminf(anv, fminf(fminf(n.x, n.y), fminf(n.z, n.w)));
    }
    float s = fmaxf(apv - anv + MARGIN_F, 0.0f);
    for (int off = 32; off; off >>= 1) s += __shfl_down(s, off);
    __shared__ float red[2];
    if ((threadIdx.x & 63) == 0) red[threadIdx.x >> 6] = s;
    __syncthreads();
    if (threadIdx.x == 0)
        atomicAdd(out, (red[0] + red[1]) / (float)N_PTS);
}

extern "C" void kernel_launch(void* const* d_in, const int* in_sizes, int n_in,
                              void* d_out, int out_size, void* d_ws, size_t ws_size,
                              hipStream_t stream) {
    const float* src   = (const float*)d_in[0];
    const float* tgt   = (const float*)d_in[1];
    const int* labels  = (const int*)d_in[2];

    char* ws = (char*)d_ws;
    const size_t featB = (size_t)N_PTS * DIM * sizeof(unsigned short);  // 4 MiB
    unsigned short* src_bf = (unsigned short*)ws;
    unsigned short* tgt_bf = (unsigned short*)(ws + featB);
    float* e1 = (float*)(ws + 2 * featB);
    float* e2 = e1 + N_PTS;
    float* ap_part = e2 + N_PTS;                 // [N_PTS][NPART] = 1 MiB
    float* an_part = ap_part + (size_t)N_PTS * NPART;

    prep_kernel<<<N_PTS / 4, 256, 0, stream>>>(src, tgt, src_bf, tgt_bf,
                                               e1, e2, (float*)d_out);
    dim3 grid(STRIPS, N_PTS / BM);
    dist_kernel<<<grid, 256, 0, stream>>>(src_bf, tgt_bf, e1, e2, labels,
                                          ap_part, an_part);
    loss_kernel<<<N_PTS / 128, 128, 0, stream>>>(ap_part, an_part, (float*)d_out);
}

// Round 9
// 101.997 us; speedup vs baseline: 1.2190x; 1.2190x over previous
//
#include <hip/hip_runtime.h>
#include <hip/hip_bf16.h>
#include <stdint.h>

#define N_PTS 4096
#define DIM 512
#define MARGIN_F 0.3f
#define POS_INF_BITS 0x7f800000

typedef short bf16x8 __attribute__((ext_vector_type(8)));
typedef float f32x4 __attribute__((ext_vector_type(4)));

__device__ __forceinline__ unsigned short f2bf(float f) {
    unsigned int b = __float_as_uint(f);
    b += 0x7FFF + ((b >> 16) & 1);   // round-to-nearest-even
    return (unsigned short)(b >> 16);
}

// async global->LDS, 16B per lane; LDS dest is wave-uniform base + lane*16
__device__ __forceinline__ void async16(const unsigned short* g, unsigned short* l) {
    __builtin_amdgcn_global_load_lds(
        (const __attribute__((address_space(1))) unsigned int*)g,
        (__attribute__((address_space(3))) unsigned int*)l,
        16, 0, 0);
}

// Raw barrier / waitcnt: keeps the compiler from emitting vmcnt(0) drains
// (hipBLASLt pattern; see round-9 notes). "memory" clobber pins ordering.
#define RAW_BARRIER()  asm volatile("s_barrier" ::: "memory")
#define WAIT_VM4()     asm volatile("s_waitcnt vmcnt(4)" ::: "memory")
#define WAIT_VM0()     asm volatile("s_waitcnt vmcnt(0)" ::: "memory")

// One wave per row: bf16 copy + exact fp32 norms; zero the output accumulator.
__global__ __launch_bounds__(256) void prep_kernel(
    const float* __restrict__ src, const float* __restrict__ tgt,
    unsigned short* __restrict__ src_bf, unsigned short* __restrict__ tgt_bf,
    float* __restrict__ e1, float* __restrict__ e2,
    float* __restrict__ out)
{
    const int row  = blockIdx.x * 4 + (threadIdx.x >> 6);
    const int lane = threadIdx.x & 63;

    if (blockIdx.x == 0 && threadIdx.x == 0) out[0] = 0.0f;

    const float4* s4 = (const float4*)(src + (size_t)row * DIM);
    const float4* t4 = (const float4*)(tgt + (size_t)row * DIM);
    float4 a0 = s4[lane], a1 = s4[lane + 64];
    float4 b0 = t4[lane], b1 = t4[lane + 64];

    ushort4 u;
    ushort4* so = (ushort4*)(src_bf + (size_t)row * DIM);
    ushort4* to = (ushort4*)(tgt_bf + (size_t)row * DIM);
    u.x = f2bf(a0.x); u.y = f2bf(a0.y); u.z = f2bf(a0.z); u.w = f2bf(a0.w); so[lane] = u;
    u.x = f2bf(a1.x); u.y = f2bf(a1.y); u.z = f2bf(a1.z); u.w = f2bf(a1.w); so[lane + 64] = u;
    u.x = f2bf(b0.x); u.y = f2bf(b0.y); u.z = f2bf(b0.z); u.w = f2bf(b0.w); to[lane] = u;
    u.x = f2bf(b1.x); u.y = f2bf(b1.y); u.z = f2bf(b1.z); u.w = f2bf(b1.w); to[lane + 64] = u;

    float s1 = a0.x*a0.x + a0.y*a0.y + a0.z*a0.z + a0.w*a0.w
             + a1.x*a1.x + a1.y*a1.y + a1.z*a1.z + a1.w*a1.w;
    float s2 = b0.x*b0.x + b0.y*b0.y + b0.z*b0.z + b0.w*b0.w
             + b1.x*b1.x + b1.y*b1.y + b1.z*b1.z + b1.w*b1.w;
    for (int off = 32; off; off >>= 1) {
        s1 += __shfl_down(s1, off);
        s2 += __shfl_down(s2, off);
    }
    if (lane == 0) {
        e1[row] = s1;
        e2[row] = s2;
    }
}

#define BM 128
#define BN 128
#define BK 32
#define NSTEP (DIM / BK)   // 16
#define NPART 64           // 32 col-blocks x 2 col-waves

// r7 structure + LDS double-buffer with raw-asm pipeline:
//   body s: issue tile s+1 -> buf[(s+1)&1]; s_waitcnt vmcnt(4) (tile-s loads,
//   issued a full iteration earlier, are done; the 4 just-issued stay in
//   flight); s_barrier (all waves' tile-s DMA landed -> safe to read);
//   compute tile s; s_barrier (all reads done -> buf may be overwritten).
// No vmcnt(0) in steady state. Lessons kept: no device fences (r4), no
// shared-line atomics (r6), XOR swizzle on the global gather (r3: 0 conflicts),
// multi-block occupancy (r8: 1 block/CU has no latency-hiding partner).
__global__ __launch_bounds__(256) void dist_kernel(
    const unsigned short* __restrict__ src_bf,
    const unsigned short* __restrict__ tgt_bf,
    const float* __restrict__ e1, const float* __restrict__ e2,
    const int* __restrict__ labels,
    float* __restrict__ ap_part, float* __restrict__ an_part)
{
    __shared__ unsigned short As[2][BM * BK];   // 2 x 8 KiB
    __shared__ unsigned short Bs[2][BN * BK];   // 2 x 8 KiB
    __shared__ int   li[BM];
    __shared__ int   lj[BN];
    __shared__ float e1s[BM];
    __shared__ float e2s[BN];

    const int i0 = blockIdx.y * BM;
    const int j0 = blockIdx.x * BN;
    const int t = threadIdx.x;
    const int lane = t & 63;
    const int wave = t >> 6;

    if (t < BM) { li[t] = labels[i0 + t]; e1s[t] = e1[i0 + t]; }
    else        { int u = t - BM; lj[u] = labels[j0 + u]; e2s[u] = e2[j0 + u]; }

    // staging: 512 16B-chunks per matrix per K-tile; thread t covers chunks
    // t (rows 0..63) and t+256 (rows 64..127). Physical chunk col = t&3 holds
    // logical chunk (t&3) ^ ((row>>1)&3); key identical for row and row+64.
    const int srow = t >> 2;                              // 0..63
    const int scol = ((t & 3) ^ ((srow >> 1) & 3)) * 8;   // swizzled source col
    const unsigned short* gA0 = src_bf + (size_t)(i0 + srow) * DIM + scol;
    const unsigned short* gA1 = src_bf + (size_t)(i0 + 64 + srow) * DIM + scol;
    const unsigned short* gB0 = tgt_bf + (size_t)(j0 + srow) * DIM + scol;
    const unsigned short* gB1 = tgt_bf + (size_t)(j0 + 64 + srow) * DIM + scol;
    const int ldsOff0 = wave * 512;          // chunk base wave*64
    const int ldsOff1 = 2048 + wave * 512;   // chunk base 256+wave*64

    // wave -> 64x64 subtile: 4x4 of 16x16x32 MFMA
    const int wm = (wave >> 1) * 64;
    const int wn = (wave & 1) * 64;
    const int fr = lane & 15;
    const int quad = lane >> 4;
    const int fkey = (fr >> 1) & 3;                       // read-side XOR key
    const int cp = (quad ^ fkey) * 8;                     // physical chunk off

    f32x4 acc[4][4];
    #pragma unroll
    for (int a = 0; a < 4; a++)
        #pragma unroll
        for (int b = 0; b < 4; b++)
            acc[a][b] = (f32x4){0.f, 0.f, 0.f, 0.f};

    // prologue: tile 0 -> buf 0
    async16(gA0, &As[0][0] + ldsOff0);
    async16(gA1, &As[0][0] + ldsOff1);
    async16(gB0, &Bs[0][0] + ldsOff0);
    async16(gB1, &Bs[0][0] + ldsOff1);

    #pragma unroll
    for (int s = 0; s < NSTEP; s++) {
        if (s + 1 < NSTEP) {
            const int kk = (s + 1) * BK;
            const int nb = (s + 1) & 1;
            async16(gA0 + kk, &As[nb][0] + ldsOff0);
            async16(gA1 + kk, &As[nb][0] + ldsOff1);
            async16(gB0 + kk, &Bs[nb][0] + ldsOff0);
            async16(gB1 + kk, &Bs[nb][0] + ldsOff1);
            WAIT_VM4();    // tile-s loads (issued last iter) done; 4 newest fly
        } else {
            WAIT_VM0();    // last tile: everything must be in
        }
        RAW_BARRIER();     // all waves' tile-s DMA landed

        const unsigned short* aa = &As[s & 1][0];
        const unsigned short* bb = &Bs[s & 1][0];
        bf16x8 af[4], bf[4];
        #pragma unroll
        for (int x = 0; x < 4; x++) {
            af[x] = *(const bf16x8*)&aa[(wm + x * 16 + fr) * BK + cp];
            bf[x] = *(const bf16x8*)&bb[(wn + x * 16 + fr) * BK + cp];
        }
        #pragma unroll
        for (int tm = 0; tm < 4; tm++)
            #pragma unroll
            for (int tn = 0; tn < 4; tn++)
                acc[tm][tn] = __builtin_amdgcn_mfma_f32_16x16x32_bf16(
                    af[tm], bf[tn], acc[tm][tn], 0, 0, 0);

        if (s + 1 < NSTEP)
            RAW_BARRIER(); // all reads of buf done -> next iter may overwrite
    }

    // epilogue: dist -> masked row max/min -> 16-lane reduce -> partial store
    const float INF = __int_as_float(POS_INF_BITS);
    const int pcol = blockIdx.x * 2 + (wave & 1);        // per-col-wave slot
    #pragma unroll
    for (int tm = 0; tm < 4; tm++) {
        #pragma unroll
        for (int r = 0; r < 4; r++) {
            const int rl = wm + tm * 16 + quad * 4 + r;  // local row
            const float e1v = e1s[rl];
            const int   liv = li[rl];
            float apv = 0.0f;   // neutral for max (dist >= 0)
            float anv = INF;
            #pragma unroll
            for (int tn = 0; tn < 4; tn++) {
                const int cl = wn + tn * 16 + fr;        // local col
                float d = e1v + e2s[cl] - 2.0f * acc[tm][tn][r];
                d = fmaxf(d, 0.0f);
                if (liv == lj[cl]) apv = fmaxf(apv, d);
                else               anv = fminf(anv, d);
            }
            #pragma unroll
            for (int off = 1; off < 16; off <<= 1) {
                apv = fmaxf(apv, __shfl_xor(apv, off));
                anv = fminf(anv, __shfl_xor(anv, off));
            }
            if (fr == 0) {
                ap_part[(size_t)(i0 + rl) * NPART + pcol] = apv;
                an_part[(size_t)(i0 + rl) * NPART + pcol] = anv;
            }
        }
    }
}

// 32 blocks x 128 threads; thread = one row: reduce 64 partials, relu, sum.
__global__ __launch_bounds__(128) void loss_kernel(
    const float* __restrict__ ap_part, const float* __restrict__ an_part,
    float* __restrict__ out)
{
    const int row = blockIdx.x * 128 + threadIdx.x;
    const float4* a4 = (const float4*)(ap_part + (size_t)row * NPART);
    const float4* n4 = (const float4*)(an_part + (size_t)row * NPART);
    float apv = 0.0f;
    float anv = __int_as_float(POS_INF_BITS);
    #pragma unroll
    for (int i = 0; i < NPART / 4; i++) {
        float4 a = a4[i], n = n4[i];
        apv = fmaxf(apv, fmaxf(fmaxf(a.x, a.y), fmaxf(a.z, a.w)));
        anv = fminf(anv, fminf(fminf(n.x, n.y), fminf(n.z, n.w)));
    }
    float s = fmaxf(apv - anv + MARGIN_F, 0.0f);
    for (int off = 32; off; off >>= 1) s += __shfl_down(s, off);
    __shared__ float red[2];
    if ((threadIdx.x & 63) == 0) red[threadIdx.x >> 6] = s;
    __syncthreads();
    if (threadIdx.x == 0)
        atomicAdd(out, (red[0] + red[1]) / (float)N_PTS);
}

extern "C" void kernel_launch(void* const* d_in, const int* in_sizes, int n_in,
                              void* d_out, int out_size, void* d_ws, size_t ws_size,
                              hipStream_t stream) {
    const float* src   = (const float*)d_in[0];
    const float* tgt   = (const float*)d_in[1];
    const int* labels  = (const int*)d_in[2];

    char* ws = (char*)d_ws;
    const size_t featB = (size_t)N_PTS * DIM * sizeof(unsigned short);  // 4 MiB
    unsigned short* src_bf = (unsigned short*)ws;
    unsigned short* tgt_bf = (unsigned short*)(ws + featB);
    float* e1 = (float*)(ws + 2 * featB);
    float* e2 = e1 + N_PTS;
    float* ap_part = e2 + N_PTS;                 // [N_PTS][NPART] = 1 MiB
    float* an_part = ap_part + (size_t)N_PTS * NPART;

    prep_kernel<<<N_PTS / 4, 256, 0, stream>>>(src, tgt, src_bf, tgt_bf,
                                               e1, e2, (float*)d_out);
    dim3 grid(N_PTS / BN, N_PTS / BM);
    dist_kernel<<<grid, 256, 0, stream>>>(src_bf, tgt_bf, e1, e2, labels,
                                          ap_part, an_part);
    loss_kernel<<<N_PTS / 128, 128, 0, stream>>>(ap_part, an_part, (float*)d_out);
}